// Round 6
// baseline (307.407 us; speedup 1.0000x reference)
//
#include <hip/hip_runtime.h>
#include <hip/hip_bf16.h>

// Problem constants (reference: DIM=768, NUM_HEADS=12, HEAD_DIM=64, GRID=32, B=8)
#define B_   8
#define N_   1024
#define C_   768
#define NH_  12
#define HD_  64
#define BH_  96
#define EPS_ 1e-6f
#define EPSN_ (1e-6f / 1024.0f)
#define SQ_  0.1803368801111244f   // 0.125 * log2(e) — Q pre-scale
#define MNEG_ (-3.0e38f)           // additive mask: exp2(-3e38) == 0.0f exactly

typedef __bf16 bf16;
typedef __attribute__((ext_vector_type(8))) __bf16  bf16x8;
typedef __attribute__((ext_vector_type(4))) __bf16  bf16x4;
typedef __attribute__((ext_vector_type(4))) float   floatx4;

#define MFMA16(a, b, c) __builtin_amdgcn_mfma_f32_16x16x32_bf16((a), (b), (c), 0, 0, 0)

// Fast exp2: raw v_exp_f32. Safe fallback is plain exp2f (known-good).
#if __has_builtin(__builtin_amdgcn_exp2f)
#define EXP2F(x) __builtin_amdgcn_exp2f(x)
#else
#define EXP2F(x) exp2f(x)
#endif

__device__ __forceinline__ void gld16(const void* g, void* l) {
  typedef unsigned int u32;
  __builtin_amdgcn_global_load_lds(
      (const __attribute__((address_space(1))) u32*)g,
      (__attribute__((address_space(3))) u32*)l, 16, 0, 0);
}
__device__ __forceinline__ float bfu2f(unsigned int u) {   // low 16 bits = bf16
  union { unsigned int i; float f; } v; v.i = u << 16; return v.f;
}
__device__ __forceinline__ float bfhi2f(unsigned int u) {  // high 16 bits = bf16
  union { unsigned int i; float f; } v; v.i = u & 0xffff0000u; return v.f;
}
__device__ __forceinline__ unsigned short f2bfu(float f) {
  union { float f; unsigned int i; } v; v.f = f;
  return (unsigned short)((v.i + 0x7FFFu + ((v.i >> 16) & 1u)) >> 16);
}

// ---------------------------------------------------------------------------
// Fused prep: x/qkv_w/proj_w fp32->bf16, rel tables fp32->bf16 scaled by 8.
// ---------------------------------------------------------------------------
__global__ __launch_bounds__(256) void prep_kernel(
    const float* __restrict__ x, const float* __restrict__ qkv_w,
    const float* __restrict__ proj_w, const float* __restrict__ relh,
    const float* __restrict__ relw,
    bf16* __restrict__ Xb, bf16* __restrict__ Wq, bf16* __restrict__ Wp,
    bf16* __restrict__ Rhb, bf16* __restrict__ Rwb) {
  int bid = blockIdx.x;
  if (bid < 8448) {                 // bulk converts
    const float* in; bf16* out; int i;
    if (bid < 6144)      { in = x;      out = Xb; i = bid * 256 + threadIdx.x; }
    else if (bid < 7872) { in = qkv_w;  out = Wq; i = (bid - 6144) * 256 + threadIdx.x; }
    else                 { in = proj_w; out = Wp; i = (bid - 7872) * 256 + threadIdx.x; }
    float4 v = ((const float4*)in)[i];
    bf16x4 o = {(bf16)v.x, (bf16)v.y, (bf16)v.z, (bf16)v.w};
    ((bf16x4*)out)[i] = o;
  } else {                          // rel tables: 63x64 -> 64x64, x8 scale
    const float* in = (bid < 8464) ? relh : relw;
    bf16* out = (bid < 8464) ? Rhb : Rwb;
    int i = ((bid < 8464) ? (bid - 8448) : (bid - 8464)) * 256 + threadIdx.x;
    int r = i >> 6;
    out[i] = (r < 63) ? (bf16)(in[i] * 8.0f) : (bf16)0.0f;
  }
}

// ---------------------------------------------------------------------------
// QKV GEMM, double-buffered LDS (unchanged).
// ---------------------------------------------------------------------------
__global__ __launch_bounds__(256) void gemm_qkv(
    const bf16* __restrict__ X, const bf16* __restrict__ W,
    const float* __restrict__ bias,
    bf16* __restrict__ Qb, bf16* __restrict__ Kb, bf16* __restrict__ Vb) {
  __shared__ __align__(16) bf16 As[2][8192];
  __shared__ __align__(16) bf16 Bs[2][8192];
  const int tid = threadIdx.x;
  const int lane = tid & 63, quad = lane >> 4, c16 = lane & 15;
  const int wid = tid >> 6;
  const int wm = (wid >> 1) * 64, wn = (wid & 1) * 64;
  const int m0 = blockIdx.x * 128, n0 = blockIdx.y * 128;
  const bool flip = (blockIdx.y < 12);    // Q and K column blocks
  floatx4 acc[4][4];
#pragma unroll
  for (int i = 0; i < 4; ++i)
#pragma unroll
    for (int j = 0; j < 4; ++j) acc[i][j] = {0.f, 0.f, 0.f, 0.f};

  auto stage = [&](int k0, int buf) {
#pragma unroll
    for (int t = 0; t < 4; ++t) {
      int task = t * 256 + tid;
      int r = task >> 3, lg = (task & 7) ^ (r & 7);
      int wbase = (t * 256 + (tid & 192)) * 8;
      gld16(X + (size_t)(m0 + r) * 768 + k0 + lg * 8, &As[buf][wbase]);
      gld16(W + (size_t)(n0 + r) * 768 + k0 + lg * 8, &Bs[buf][wbase]);
    }
  };

  stage(0, 0);
  for (int it = 0; it < 12; ++it) {
    const int cur = it & 1;
    __syncthreads();                       // drains stage(it); orders WAR for it+1
    if (it < 11) stage((it + 1) * 64, cur ^ 1);
#pragma unroll
    for (int kw = 0; kw < 2; ++kw) {
      bf16x8 af[4], bfr[4];
#pragma unroll
      for (int i = 0; i < 4; ++i) {
        int r = wm + i * 16 + c16, pg = (kw * 4 + quad) ^ (c16 & 7);
        af[i] = *(bf16x8*)&As[cur][r * 64 + pg * 8];
      }
#pragma unroll
      for (int j = 0; j < 4; ++j) {
        int r = wn + j * 16 + c16, pg = (kw * 4 + quad) ^ (c16 & 7);
        bfr[j] = *(bf16x8*)&Bs[cur][r * 64 + pg * 8];
      }
      if (flip) {
#pragma unroll
        for (int a = 0; a < 4; ++a)
#pragma unroll
          for (int b = 0; b < 4; ++b) acc[a][b] = MFMA16(bfr[a], af[b], acc[a][b]);
      } else {
#pragma unroll
        for (int i = 0; i < 4; ++i)
#pragma unroll
          for (int j = 0; j < 4; ++j) acc[i][j] = MFMA16(af[i], bfr[j], acc[i][j]);
      }
    }
  }
  if (flip) {
    const bool isQ = (blockIdx.y < 6);
    bf16* base = isQ ? Qb : Kb;
    const int off = isQ ? 0 : 768;
#pragma unroll
    for (int a = 0; a < 4; ++a) {
      int jb = n0 + wn + a * 16 + quad * 4;
      float4 b4 = *(const float4*)&bias[jb];
      int head = (jb - off) >> 6;
      int d = jb & 63;
#pragma unroll
      for (int b = 0; b < 4; ++b) {
        int tok = m0 + wm + b * 16 + c16;
        int bb = tok >> 10, n = tok & 1023;
        float v0 = acc[a][b][0] + b4.x, v1 = acc[a][b][1] + b4.y;
        float v2 = acc[a][b][2] + b4.z, v3 = acc[a][b][3] + b4.w;
        if (isQ) { v0 *= SQ_; v1 *= SQ_; v2 *= SQ_; v3 *= SQ_; }
        bf16x4 o = {(bf16)v0, (bf16)v1, (bf16)v2, (bf16)v3};
        *(bf16x4*)&base[(((size_t)bb * NH_ + head) * N_ + n) * HD_ + d] = o;
      }
    }
  } else {
#pragma unroll
    for (int jt = 0; jt < 4; ++jt) {
      int j = n0 + wn + jt * 16 + c16;
      float bj = bias[j];
      int rem = j - 1536, head = rem >> 6, d = rem & 63;
#pragma unroll
      for (int it = 0; it < 4; ++it) {
        int mbase = m0 + wm + it * 16 + quad * 4;
        int bb = mbase >> 10, n = mbase & 1023;
        bf16x4 o = {(bf16)(acc[it][jt][0] + bj), (bf16)(acc[it][jt][1] + bj),
                    (bf16)(acc[it][jt][2] + bj), (bf16)(acc[it][jt][3] + bj)};
        *(bf16x4*)&Vb[(((size_t)bb * NH_ + head) * HD_ + d) * N_ + n] = o;
      }
    }
  }
}

// ---------------------------------------------------------------------------
// Flash attention, R14 = R13 + Vsum folded in via ones-A MFMA (vsum_kernel
// dispatch removed). Every block already stages all 16 V tiles, and the
// MFMA pipe is 81% idle: vs_acc[dt] = MFMA(ones, bv, vs_acc) gives
// D[m][n] = sum_k V[n][k] (A=ones is fragment-layout-invariant), so after
// the loop vs_acc[dt][0] IS Vsum[d=dt*16+c16] in the epilogue layout —
// no shuffles, no global read, one fewer kernel + inter-dispatch gap.
// NOTE: the EPSN*Vsum term cannot be dropped: when a row's max column is
// masked, the reference denominator collapses to EPS and this term
// contributes at the 1e-3 level (> threshold).
// ---------------------------------------------------------------------------
__global__ __launch_bounds__(512, 6) void attn_mfma(
    const bf16* __restrict__ Qb, const bf16* __restrict__ Kb,
    const bf16* __restrict__ Vb, const float* __restrict__ policy,
    const bf16* __restrict__ Rh, const bf16* __restrict__ Rw,
    bf16* __restrict__ AO) {
  const int bh = blockIdx.x, qt = blockIdx.y;      // qt: 128-row q tile index
  const int b = bh / NH_, head = bh % NH_;
  __shared__ __align__(16) bf16 Ks[2][4096];       // K tiles, pi-permuted rows
  __shared__ __align__(16) bf16 Vt[2][4096];       // V tiles [d][k]
  __shared__ unsigned int RHb[128 * 17];           // [q][kt] u32, stride-17 pad
  unsigned short* RWb = (unsigned short*)Ks;       // [q][kcol], prologue-only alias
  const int tid = threadIdx.x;
  const int wid = tid >> 6, lane = tid & 63, quad = lane >> 4, c16 = lane & 15;
  const int sw = c16 & 7;
  const int qloc = wid * 16 + c16;                 // this lane's q row [0,128)
  const floatx4 zero4 = {0.f, 0.f, 0.f, 0.f};

  const bf16* Qg = Qb + ((size_t)bh * N_ + qt * 128) * HD_;
  const bf16* Kg = Kb + (size_t)bh * (N_ * HD_);
  const bf16* Vg = Vb + (size_t)bh * (N_ * HD_);

  // Staging: tid-only address parts hoisted once; per-kt only the tile
  // offset varies. K rows pi-permuted + column-XOR via the global SOURCE
  // address (LDS dest stays linear, wave-uniform base + lane*16).
  const int sp = tid >> 3, sg = tid & 7;
  const int Tk = 32 * (sp >> 5) + 4 * ((sp >> 4) & 1) + 8 * ((sp >> 2) & 3) + (sp & 3);
  const int koff = (sg ^ (sp & 7)) * 8;
  const bf16* kbase = Kg + (size_t)Tk * 64 + koff;
  const bf16* vbase = Vg + (size_t)sp * N_ + koff;
  const int wbase = (tid & 448) * 8;               // wave-uniform LDS base
  auto stageKV = [&](int kt2, int buf) {
    gld16(kbase + (size_t)kt2 * 4096, &Ks[buf][wbase]);
    gld16(vbase + kt2 * 64, &Vt[buf][wbase]);
  };

  // K/V tile 0 -> buffer 1; latency hides under the whole prologue
  stageKV(0, 1);

  // policy -> per-thread packed mask bits (16 bits per kt). Diagonal k tile
  // is per-thread: dkt = 2*qt + (qloc>>6); k-in-tile kd = qloc&63.
  unsigned long long p64[4] = {0ull, 0ull, 0ull, 0ull};
  {
    const float* Pg = policy + (size_t)b * N_;
    const int kd = qloc & 63;
    const int dkt = 2 * qt + (qloc >> 6);
#pragma unroll
    for (int kt = 0; kt < 16; ++kt) {
      unsigned long long bal = __ballot(Pg[kt * 64 + lane] != 0.0f);
      unsigned int w16 = (((unsigned int)bal >> (8 * quad)) & 0xFFu)
                       | ((((unsigned int)(bal >> 32) >> (8 * quad)) & 0xFFu) << 8);
      if (kt == dkt && quad == ((kd >> 3) & 3))
        w16 |= 1u << (((kd >> 5) << 3) | (kd & 7));   // diagonal unmasked
      p64[kt >> 2] |= (unsigned long long)w16 << (16 * (kt & 3));
    }
  }

  // Q fragments straight from global (A- and B-role layouts are identical)
  bf16x8 qf0 = *(const bf16x8*)(Qg + qloc * 64 + quad * 8);
  bf16x8 qf1 = *(const bf16x8*)(Qg + qloc * 64 + 32 + quad * 8);

  // QRh -> RHb[q][kgr] (bf16 bits; rows wave-private). Rh B-frags from global.
  {
    floatx4 racc[4];
#pragma unroll
    for (int nt = 0; nt < 4; ++nt) {
      int r = nt * 16 + c16;
      bf16x8 b0 = *(const bf16x8*)(Rh + r * 64 + quad * 8);
      bf16x8 b1 = *(const bf16x8*)(Rh + r * 64 + 32 + quad * 8);
      racc[nt] = MFMA16(qf1, b1, MFMA16(qf0, b0, zero4));
    }
#pragma unroll
    for (int nt = 0; nt < 4; ++nt)
#pragma unroll
      for (int reg = 0; reg < 4; ++reg) {
        int rloc = wid * 16 + quad * 4 + reg;
        int hh = 4 * qt + (rloc >> 5);             // global h of q row rloc
        int krow = hh + 31 - (nt * 16 + c16);
        if ((unsigned)krow < 32u)
          ((unsigned short*)RHb)[rloc * 34 + krow] = f2bfu(racc[nt][reg]);
      }
  }
  // QRw -> RWb[q][kcol]
  {
    floatx4 racc[4];
#pragma unroll
    for (int nt = 0; nt < 4; ++nt) {
      int r = nt * 16 + c16;
      bf16x8 b0 = *(const bf16x8*)(Rw + r * 64 + quad * 8);
      bf16x8 b1 = *(const bf16x8*)(Rw + r * 64 + 32 + quad * 8);
      racc[nt] = MFMA16(qf1, b1, MFMA16(qf0, b0, zero4));
    }
#pragma unroll
    for (int nt = 0; nt < 4; ++nt)
#pragma unroll
      for (int reg = 0; reg < 4; ++reg) {
        int rloc = wid * 16 + quad * 4 + reg;
        int kcol = (rloc & 31) + 31 - (nt * 16 + c16);   // qg&31 == rloc&31
        if ((unsigned)kcol < 32u) RWb[rloc * 32 + kcol] = f2bfu(racc[nt][reg]);
      }
  }

  // hoist rw: lane's slot (t,reg) has kcol = 8*quad+4*(t&1)+reg (kt-invariant)
  float rwv[2][4];
#pragma unroll
  for (int p = 0; p < 2; ++p)
#pragma unroll
    for (int reg = 0; reg < 4; ++reg)
      rwv[p][reg] = bfu2f(RWb[qloc * 32 + 8 * quad + 4 * p + reg]);

  floatx4 o_acc[4];
#pragma unroll
  for (int i = 0; i < 4; ++i) o_acc[i] = zero4;
  floatx4 o_l = zero4;                             // l via MFMA(P, ones)
  floatx4 vs_acc[4];                               // Vsum via MFMA(ones, V)
#pragma unroll
  for (int i = 0; i < 4; ++i) vs_acc[i] = zero4;
  bf16x8 vone;
#pragma unroll
  for (int e = 0; e < 8; ++e) vone[e] = (bf16)1.0f;

  // 256-bit mask shift chain (no runtime-indexed register arrays)
  unsigned long long mm0 = p64[0], mm1 = p64[1], mm2 = p64[2], mm3 = p64[3];

  // tile kt lives in buffer (kt+1)&1 (tile 0 went to buf 1)
  for (int kt = 0; kt < 16; ++kt) {
    const int cur = (kt + 1) & 1;
    __syncthreads();                 // drains stage(kt); orders WAR for stage(kt+1)
    if (kt < 15) stageKV(kt + 1, kt & 1);

    // C-init = rh + rw, masked to MNEG via policy bits (built while loads fly)
    unsigned int w = (unsigned int)mm0 & 0xFFFFu;
    mm0 = (mm0 >> 16) | (mm1 << 48);
    mm1 = (mm1 >> 16) | (mm2 << 48);
    mm2 = (mm2 >> 16) | (mm3 << 48);
    mm3 >>= 16;
    unsigned int rhp = RHb[qloc * 17 + kt];
    float rh0 = bfu2f(rhp & 0xffffu), rh1 = bfhi2f(rhp);
    floatx4 init[4];
#pragma unroll
    for (int t = 0; t < 4; ++t) {
      float rh = (t < 2) ? rh0 : rh1;
#pragma unroll
      for (int reg = 0; reg < 4; ++reg) {
        float base = rh + rwv[t & 1][reg];
        init[t][reg] = ((w >> ((t >> 1) * 8 + (t & 1) * 4 + reg)) & 1u) ? base : MNEG_;
      }
    }

    // S' = K.Q^T + init (rows = pi-permuted k tokens, cols = q)
    floatx4 s[4];
#pragma unroll
    for (int t = 0; t < 4; ++t) {
      int r = t * 16 + c16;
      bf16x8 ak0 = *(bf16x8*)&Ks[cur][r * 64 + (quad ^ sw) * 8];
      bf16x8 ak1 = *(bf16x8*)&Ks[cur][r * 64 + ((4 + quad) ^ sw) * 8];
      s[t] = MFMA16(ak1, qf1, MFMA16(ak0, qf0, init[t]));
    }

    // exp (raw v_exp_f32) -> bf16 via COMPILER casts (hazard-scheduled);
    // all indices compile-time after unroll (rule #20).
    float ev[4][4];
#pragma unroll
    for (int t = 0; t < 4; ++t)
#pragma unroll
      for (int reg = 0; reg < 4; ++reg) ev[t][reg] = EXP2F(s[t][reg]);

    // PV: O += P.V, A-frag assembled in-register; l rides a ones-A MFMA;
    // Vsum rides ones-A MFMAs on the already-loaded V fragments.
#pragma unroll
    for (int kw2 = 0; kw2 < 2; ++kw2) {
      bf16x8 apv;
#pragma unroll
      for (int j = 0; j < 8; ++j)
        apv[j] = (bf16)ev[2 * kw2 + (j >> 2)][j & 3];
      o_l = MFMA16(apv, vone, o_l);
#pragma unroll
      for (int dt = 0; dt < 4; ++dt) {
        int r = dt * 16 + c16;
        bf16x8 bv = *(bf16x8*)&Vt[cur][r * 64 + ((kw2 * 4 + quad) ^ sw) * 8];
        o_acc[dt] = MFMA16(apv, bv, o_acc[dt]);
        vs_acc[dt] = MFMA16(vone, bv, vs_acc[dt]);
      }
    }
  }

  // o_l[reg] is the COMPLETE l for q = quad*4+reg; vs_acc[dt][*] (all regs
  // equal) is the COMPLETE Vsum for d = dt*16+c16. No shuffles, no loads.
  float inv[4];
#pragma unroll
  for (int reg = 0; reg < 4; ++reg) inv[reg] = 1.f / (o_l[reg] + EPS_);

#pragma unroll
  for (int dt = 0; dt < 4; ++dt) {
    int d = dt * 16 + c16;
    float vs = vs_acc[dt][0];
#pragma unroll
    for (int reg = 0; reg < 4; ++reg) {
      int nq = qt * 128 + wid * 16 + quad * 4 + reg;
      float o = (o_acc[dt][reg] + EPSN_ * vs) * inv[reg];
      AO[((size_t)b * N_ + nq) * C_ + head * HD_ + d] = (bf16)o;
    }
  }
}

// ---------------------------------------------------------------------------
// Proj GEMM, double-buffered LDS, flip orientation (float4 stores).
// ---------------------------------------------------------------------------
__global__ __launch_bounds__(256) void gemm_proj(
    const bf16* __restrict__ A, const bf16* __restrict__ W,
    const float* __restrict__ bias, float* __restrict__ Out) {
  __shared__ __align__(16) bf16 As[2][8192];
  __shared__ __align__(16) bf16 Bs[2][8192];
  const int tid = threadIdx.x;
  const int lane = tid & 63, quad = lane >> 4, c16 = lane & 15;
  const int wid = tid >> 6;
  const int wm = (wid >> 1) * 64, wn = (wid & 1) * 64;
  const int m0 = blockIdx.x * 128, n0 = blockIdx.y * 128;
  floatx4 acc[4][4];
#pragma unroll
  for (int i = 0; i < 4; ++i)
#pragma unroll
    for (int j = 0; j < 4; ++j) acc[i][j] = {0.f, 0.f, 0.f, 0.f};

  auto stage = [&](int k0, int buf) {
#pragma unroll
    for (int t = 0; t < 4; ++t) {
      int task = t * 256 + tid;
      int r = task >> 3, lg = (task & 7) ^ (r & 7);
      int wbase = (t * 256 + (tid & 192)) * 8;
      gld16(A + (size_t)(m0 + r) * 768 + k0 + lg * 8, &As[buf][wbase]);
      gld16(W + (size_t)(n0 + r) * 768 + k0 + lg * 8, &Bs[buf][wbase]);
    }
  };

  stage(0, 0);
  for (int it = 0; it < 12; ++it) {
    const int cur = it & 1;
    __syncthreads();
    if (it < 11) stage((it + 1) * 64, cur ^ 1);
#pragma unroll
    for (int kw = 0; kw < 2; ++kw) {
      bf16x8 af[4], bfr[4];
#pragma unroll
      for (int i = 0; i < 4; ++i) {
        int r = wm + i * 16 + c16, pg = (kw * 4 + quad) ^ (c16 & 7);
        af[i] = *(bf16x8*)&As[cur][r * 64 + pg * 8];
      }
#pragma unroll
      for (int j = 0; j < 4; ++j) {
        int r = wn + j * 16 + c16, pg = (kw * 4 + quad) ^ (c16 & 7);
        bfr[j] = *(bf16x8*)&Bs[cur][r * 64 + pg * 8];
      }
#pragma unroll
      for (int a = 0; a < 4; ++a)
#pragma unroll
        for (int b = 0; b < 4; ++b) acc[a][b] = MFMA16(bfr[a], af[b], acc[a][b]);
    }
  }
#pragma unroll
  for (int a = 0; a < 4; ++a) {
    int jb = n0 + wn + a * 16 + quad * 4;
    float4 b4 = *(const float4*)&bias[jb];
#pragma unroll
    for (int b = 0; b < 4; ++b) {
      int m = m0 + wm + b * 16 + c16;
      float4 o = make_float4(acc[a][b][0] + b4.x, acc[a][b][1] + b4.y,
                             acc[a][b][2] + b4.z, acc[a][b][3] + b4.w);
      *(float4*)&Out[(size_t)m * 768 + jb] = o;
    }
  }
}

extern "C" void kernel_launch(void* const* d_in, const int* in_sizes, int n_in,
                              void* d_out, int out_size, void* d_ws, size_t ws_size,
                              hipStream_t stream) {
  const float* x      = (const float*)d_in[0];
  const float* policy = (const float*)d_in[1];
  const float* qkv_w  = (const float*)d_in[2];
  const float* qkv_b  = (const float*)d_in[3];
  const float* proj_w = (const float*)d_in[4];
  const float* proj_b = (const float*)d_in[5];
  const float* relh   = (const float*)d_in[6];
  const float* relw   = (const float*)d_in[7];

  char* ws = (char*)d_ws;
  bf16* Xbf   = (bf16*)(ws);                    // 12,582,912 B
  bf16* Wqkv  = (bf16*)(ws + 12582912);         //  3,538,944 B
  bf16* Wproj = (bf16*)(ws + 16121856);         //  1,179,648 B
  bf16* Rhb   = (bf16*)(ws + 17301504);         //      8,192 B
  bf16* Rwb   = (bf16*)(ws + 17309696);         //      8,192 B
  bf16* Qb    = (bf16*)(ws + 17317888);         // 12,582,912 B
  bf16* Kb    = (bf16*)(ws + 29900800);
  bf16* Vb    = (bf16*)(ws + 42483712);         // [bh][d][n] layout
  bf16* AOb   = (bf16*)(ws + 55066624);

  prep_kernel<<<8480, 256, 0, stream>>>(x, qkv_w, proj_w, relh, relw,
                                        Xbf, Wqkv, Wproj, Rhb, Rwb);
  gemm_qkv<<<dim3(64, 18), 256, 0, stream>>>(Xbf, Wqkv, qkv_b, Qb, Kb, Vb);
  attn_mfma<<<dim3(BH_, 8), 512, 0, stream>>>(Qb, Kb, Vb, policy, Rhb, Rwb,
                                              AOb);
  gemm_proj<<<dim3(64, 6), 256, 0, stream>>>(AOb, Wproj, proj_b, (float*)d_out);
}

// Round 7
// 216.804 us; speedup vs baseline: 1.4179x; 1.4179x over previous
//
#include <hip/hip_runtime.h>
#include <hip/hip_bf16.h>

// Problem constants (reference: DIM=768, NUM_HEADS=12, HEAD_DIM=64, GRID=32, B=8)
#define B_   8
#define N_   1024
#define C_   768
#define NH_  12
#define HD_  64
#define BH_  96
#define EPS_ 1e-6f
#define EPSN_ (1e-6f / 1024.0f)
#define SQ_  0.1803368801111244f   // 0.125 * log2(e) — Q pre-scale
#define MNEG_ (-3.0e38f)           // additive mask: exp2(-3e38) == 0.0f exactly

typedef __bf16 bf16;
typedef __attribute__((ext_vector_type(8))) __bf16  bf16x8;
typedef __attribute__((ext_vector_type(4))) __bf16  bf16x4;
typedef __attribute__((ext_vector_type(4))) float   floatx4;

#define MFMA16(a, b, c) __builtin_amdgcn_mfma_f32_16x16x32_bf16((a), (b), (c), 0, 0, 0)

// Fast exp2: raw v_exp_f32. Safe fallback is plain exp2f (known-good).
#if __has_builtin(__builtin_amdgcn_exp2f)
#define EXP2F(x) __builtin_amdgcn_exp2f(x)
#else
#define EXP2F(x) exp2f(x)
#endif

__device__ __forceinline__ void gld16(const void* g, void* l) {
  typedef unsigned int u32;
  __builtin_amdgcn_global_load_lds(
      (const __attribute__((address_space(1))) u32*)g,
      (__attribute__((address_space(3))) u32*)l, 16, 0, 0);
}
__device__ __forceinline__ float bfu2f(unsigned int u) {   // low 16 bits = bf16
  union { unsigned int i; float f; } v; v.i = u << 16; return v.f;
}
__device__ __forceinline__ float bfhi2f(unsigned int u) {  // high 16 bits = bf16
  union { unsigned int i; float f; } v; v.i = u & 0xffff0000u; return v.f;
}
__device__ __forceinline__ unsigned short f2bfu(float f) {
  union { float f; unsigned int i; } v; v.f = f;
  return (unsigned short)((v.i + 0x7FFFu + ((v.i >> 16) & 1u)) >> 16);
}

// ---------------------------------------------------------------------------
// Fused prep: x/qkv_w/proj_w fp32->bf16, rel tables fp32->bf16 scaled by 8.
// ---------------------------------------------------------------------------
__global__ __launch_bounds__(256) void prep_kernel(
    const float* __restrict__ x, const float* __restrict__ qkv_w,
    const float* __restrict__ proj_w, const float* __restrict__ relh,
    const float* __restrict__ relw,
    bf16* __restrict__ Xb, bf16* __restrict__ Wq, bf16* __restrict__ Wp,
    bf16* __restrict__ Rhb, bf16* __restrict__ Rwb) {
  int bid = blockIdx.x;
  if (bid < 8448) {                 // bulk converts
    const float* in; bf16* out; int i;
    if (bid < 6144)      { in = x;      out = Xb; i = bid * 256 + threadIdx.x; }
    else if (bid < 7872) { in = qkv_w;  out = Wq; i = (bid - 6144) * 256 + threadIdx.x; }
    else                 { in = proj_w; out = Wp; i = (bid - 7872) * 256 + threadIdx.x; }
    float4 v = ((const float4*)in)[i];
    bf16x4 o = {(bf16)v.x, (bf16)v.y, (bf16)v.z, (bf16)v.w};
    ((bf16x4*)out)[i] = o;
  } else {                          // rel tables: 63x64 -> 64x64, x8 scale
    const float* in = (bid < 8464) ? relh : relw;
    bf16* out = (bid < 8464) ? Rhb : Rwb;
    int i = ((bid < 8464) ? (bid - 8448) : (bid - 8464)) * 256 + threadIdx.x;
    int r = i >> 6;
    out[i] = (r < 63) ? (bf16)(in[i] * 8.0f) : (bf16)0.0f;
  }
}

// ---------------------------------------------------------------------------
// QKV GEMM, double-buffered LDS (unchanged).
// ---------------------------------------------------------------------------
__global__ __launch_bounds__(256) void gemm_qkv(
    const bf16* __restrict__ X, const bf16* __restrict__ W,
    const float* __restrict__ bias,
    bf16* __restrict__ Qb, bf16* __restrict__ Kb, bf16* __restrict__ Vb) {
  __shared__ __align__(16) bf16 As[2][8192];
  __shared__ __align__(16) bf16 Bs[2][8192];
  const int tid = threadIdx.x;
  const int lane = tid & 63, quad = lane >> 4, c16 = lane & 15;
  const int wid = tid >> 6;
  const int wm = (wid >> 1) * 64, wn = (wid & 1) * 64;
  const int m0 = blockIdx.x * 128, n0 = blockIdx.y * 128;
  const bool flip = (blockIdx.y < 12);    // Q and K column blocks
  floatx4 acc[4][4];
#pragma unroll
  for (int i = 0; i < 4; ++i)
#pragma unroll
    for (int j = 0; j < 4; ++j) acc[i][j] = {0.f, 0.f, 0.f, 0.f};

  auto stage = [&](int k0, int buf) {
#pragma unroll
    for (int t = 0; t < 4; ++t) {
      int task = t * 256 + tid;
      int r = task >> 3, lg = (task & 7) ^ (r & 7);
      int wbase = (t * 256 + (tid & 192)) * 8;
      gld16(X + (size_t)(m0 + r) * 768 + k0 + lg * 8, &As[buf][wbase]);
      gld16(W + (size_t)(n0 + r) * 768 + k0 + lg * 8, &Bs[buf][wbase]);
    }
  };

  stage(0, 0);
  for (int it = 0; it < 12; ++it) {
    const int cur = it & 1;
    __syncthreads();                       // drains stage(it); orders WAR for it+1
    if (it < 11) stage((it + 1) * 64, cur ^ 1);
#pragma unroll
    for (int kw = 0; kw < 2; ++kw) {
      bf16x8 af[4], bfr[4];
#pragma unroll
      for (int i = 0; i < 4; ++i) {
        int r = wm + i * 16 + c16, pg = (kw * 4 + quad) ^ (c16 & 7);
        af[i] = *(bf16x8*)&As[cur][r * 64 + pg * 8];
      }
#pragma unroll
      for (int j = 0; j < 4; ++j) {
        int r = wn + j * 16 + c16, pg = (kw * 4 + quad) ^ (c16 & 7);
        bfr[j] = *(bf16x8*)&Bs[cur][r * 64 + pg * 8];
      }
      if (flip) {
#pragma unroll
        for (int a = 0; a < 4; ++a)
#pragma unroll
          for (int b = 0; b < 4; ++b) acc[a][b] = MFMA16(bfr[a], af[b], acc[a][b]);
      } else {
#pragma unroll
        for (int i = 0; i < 4; ++i)
#pragma unroll
          for (int j = 0; j < 4; ++j) acc[i][j] = MFMA16(af[i], bfr[j], acc[i][j]);
      }
    }
  }
  if (flip) {
    const bool isQ = (blockIdx.y < 6);
    bf16* base = isQ ? Qb : Kb;
    const int off = isQ ? 0 : 768;
#pragma unroll
    for (int a = 0; a < 4; ++a) {
      int jb = n0 + wn + a * 16 + quad * 4;
      float4 b4 = *(const float4*)&bias[jb];
      int head = (jb - off) >> 6;
      int d = jb & 63;
#pragma unroll
      for (int b = 0; b < 4; ++b) {
        int tok = m0 + wm + b * 16 + c16;
        int bb = tok >> 10, n = tok & 1023;
        float v0 = acc[a][b][0] + b4.x, v1 = acc[a][b][1] + b4.y;
        float v2 = acc[a][b][2] + b4.z, v3 = acc[a][b][3] + b4.w;
        if (isQ) { v0 *= SQ_; v1 *= SQ_; v2 *= SQ_; v3 *= SQ_; }
        bf16x4 o = {(bf16)v0, (bf16)v1, (bf16)v2, (bf16)v3};
        *(bf16x4*)&base[(((size_t)bb * NH_ + head) * N_ + n) * HD_ + d] = o;
      }
    }
  } else {
#pragma unroll
    for (int jt = 0; jt < 4; ++jt) {
      int j = n0 + wn + jt * 16 + c16;
      float bj = bias[j];
      int rem = j - 1536, head = rem >> 6, d = rem & 63;
#pragma unroll
      for (int it = 0; it < 4; ++it) {
        int mbase = m0 + wm + it * 16 + quad * 4;
        int bb = mbase >> 10, n = mbase & 1023;
        bf16x4 o = {(bf16)(acc[it][jt][0] + bj), (bf16)(acc[it][jt][1] + bj),
                    (bf16)(acc[it][jt][2] + bj), (bf16)(acc[it][jt][3] + bj)};
        *(bf16x4*)&Vb[(((size_t)bb * NH_ + head) * HD_ + d) * N_ + n] = o;
      }
    }
  }
}

// ---------------------------------------------------------------------------
// Flash attention, R15: R6 fold kept, register cost deleted. R6 post-mortem:
// vs_acc[4] (+16 persistent regs) blew the (512,6) budget (~85 VGPR+AGPR) ->
// inner-loop scratch spill, 520 MB of HBM traffic, 157us. Fix via algebra:
//   O = sum_k (P+EPSN)[q,k] V[k,d] / (sum_k e + EPS)
// i.e. fold EPSN into P BEFORE the PV MFMA (apv = bf16(e + EPSN)). Then the
// ones-MFMA denominator o_l = sum(P+EPSN) = sum(e) + 1024*EPSN = sum(e)+EPS
// EXACTLY the reference denominator -> inv = 1/o_l, no Vsum accumulator, no
// vsum kernel, no Vsum read. Cost: 16 v_add_f32/kt. Registers back to the
// R5 footprint that fit without spilling.
// ---------------------------------------------------------------------------
__global__ __launch_bounds__(512, 6) void attn_mfma(
    const bf16* __restrict__ Qb, const bf16* __restrict__ Kb,
    const bf16* __restrict__ Vb, const float* __restrict__ policy,
    const bf16* __restrict__ Rh, const bf16* __restrict__ Rw,
    bf16* __restrict__ AO) {
  const int bh = blockIdx.x, qt = blockIdx.y;      // qt: 128-row q tile index
  const int b = bh / NH_, head = bh % NH_;
  __shared__ __align__(16) bf16 Ks[2][4096];       // K tiles, pi-permuted rows
  __shared__ __align__(16) bf16 Vt[2][4096];       // V tiles [d][k]
  __shared__ unsigned int RHb[128 * 17];           // [q][kt] u32, stride-17 pad
  unsigned short* RWb = (unsigned short*)Ks;       // [q][kcol], prologue-only alias
  const int tid = threadIdx.x;
  const int wid = tid >> 6, lane = tid & 63, quad = lane >> 4, c16 = lane & 15;
  const int sw = c16 & 7;
  const int qloc = wid * 16 + c16;                 // this lane's q row [0,128)
  const floatx4 zero4 = {0.f, 0.f, 0.f, 0.f};

  const bf16* Qg = Qb + ((size_t)bh * N_ + qt * 128) * HD_;
  const bf16* Kg = Kb + (size_t)bh * (N_ * HD_);
  const bf16* Vg = Vb + (size_t)bh * (N_ * HD_);

  // Staging: tid-only address parts hoisted once; per-kt only the tile
  // offset varies. K rows pi-permuted + column-XOR via the global SOURCE
  // address (LDS dest stays linear, wave-uniform base + lane*16).
  const int sp = tid >> 3, sg = tid & 7;
  const int Tk = 32 * (sp >> 5) + 4 * ((sp >> 4) & 1) + 8 * ((sp >> 2) & 3) + (sp & 3);
  const int koff = (sg ^ (sp & 7)) * 8;
  const bf16* kbase = Kg + (size_t)Tk * 64 + koff;
  const bf16* vbase = Vg + (size_t)sp * N_ + koff;
  const int wbase = (tid & 448) * 8;               // wave-uniform LDS base
  auto stageKV = [&](int kt2, int buf) {
    gld16(kbase + (size_t)kt2 * 4096, &Ks[buf][wbase]);
    gld16(vbase + kt2 * 64, &Vt[buf][wbase]);
  };

  // K/V tile 0 -> buffer 1; latency hides under the whole prologue
  stageKV(0, 1);

  // policy -> per-thread packed mask bits (16 bits per kt). Diagonal k tile
  // is per-thread: dkt = 2*qt + (qloc>>6); k-in-tile kd = qloc&63.
  unsigned long long p64[4] = {0ull, 0ull, 0ull, 0ull};
  {
    const float* Pg = policy + (size_t)b * N_;
    const int kd = qloc & 63;
    const int dkt = 2 * qt + (qloc >> 6);
#pragma unroll
    for (int kt = 0; kt < 16; ++kt) {
      unsigned long long bal = __ballot(Pg[kt * 64 + lane] != 0.0f);
      unsigned int w16 = (((unsigned int)bal >> (8 * quad)) & 0xFFu)
                       | ((((unsigned int)(bal >> 32) >> (8 * quad)) & 0xFFu) << 8);
      if (kt == dkt && quad == ((kd >> 3) & 3))
        w16 |= 1u << (((kd >> 5) << 3) | (kd & 7));   // diagonal unmasked
      p64[kt >> 2] |= (unsigned long long)w16 << (16 * (kt & 3));
    }
  }

  // Q fragments straight from global (A- and B-role layouts are identical)
  bf16x8 qf0 = *(const bf16x8*)(Qg + qloc * 64 + quad * 8);
  bf16x8 qf1 = *(const bf16x8*)(Qg + qloc * 64 + 32 + quad * 8);

  // QRh -> RHb[q][kgr] (bf16 bits; rows wave-private). Rh B-frags from global.
  {
    floatx4 racc[4];
#pragma unroll
    for (int nt = 0; nt < 4; ++nt) {
      int r = nt * 16 + c16;
      bf16x8 b0 = *(const bf16x8*)(Rh + r * 64 + quad * 8);
      bf16x8 b1 = *(const bf16x8*)(Rh + r * 64 + 32 + quad * 8);
      racc[nt] = MFMA16(qf1, b1, MFMA16(qf0, b0, zero4));
    }
#pragma unroll
    for (int nt = 0; nt < 4; ++nt)
#pragma unroll
      for (int reg = 0; reg < 4; ++reg) {
        int rloc = wid * 16 + quad * 4 + reg;
        int hh = 4 * qt + (rloc >> 5);             // global h of q row rloc
        int krow = hh + 31 - (nt * 16 + c16);
        if ((unsigned)krow < 32u)
          ((unsigned short*)RHb)[rloc * 34 + krow] = f2bfu(racc[nt][reg]);
      }
  }
  // QRw -> RWb[q][kcol]
  {
    floatx4 racc[4];
#pragma unroll
    for (int nt = 0; nt < 4; ++nt) {
      int r = nt * 16 + c16;
      bf16x8 b0 = *(const bf16x8*)(Rw + r * 64 + quad * 8);
      bf16x8 b1 = *(const bf16x8*)(Rw + r * 64 + 32 + quad * 8);
      racc[nt] = MFMA16(qf1, b1, MFMA16(qf0, b0, zero4));
    }
#pragma unroll
    for (int nt = 0; nt < 4; ++nt)
#pragma unroll
      for (int reg = 0; reg < 4; ++reg) {
        int rloc = wid * 16 + quad * 4 + reg;
        int kcol = (rloc & 31) + 31 - (nt * 16 + c16);   // qg&31 == rloc&31
        if ((unsigned)kcol < 32u) RWb[rloc * 32 + kcol] = f2bfu(racc[nt][reg]);
      }
  }

  // hoist rw: lane's slot (t,reg) has kcol = 8*quad+4*(t&1)+reg (kt-invariant)
  float rwv[2][4];
#pragma unroll
  for (int p = 0; p < 2; ++p)
#pragma unroll
    for (int reg = 0; reg < 4; ++reg)
      rwv[p][reg] = bfu2f(RWb[qloc * 32 + 8 * quad + 4 * p + reg]);

  floatx4 o_acc[4];
#pragma unroll
  for (int i = 0; i < 4; ++i) o_acc[i] = zero4;
  floatx4 o_l = zero4;                             // l via MFMA(P', ones)
  bf16x8 vone;
#pragma unroll
  for (int e = 0; e < 8; ++e) vone[e] = (bf16)1.0f;

  // 256-bit mask shift chain (no runtime-indexed register arrays)
  unsigned long long mm0 = p64[0], mm1 = p64[1], mm2 = p64[2], mm3 = p64[3];

  // tile kt lives in buffer (kt+1)&1 (tile 0 went to buf 1)
  for (int kt = 0; kt < 16; ++kt) {
    const int cur = (kt + 1) & 1;
    __syncthreads();                 // drains stage(kt); orders WAR for stage(kt+1)
    if (kt < 15) stageKV(kt + 1, kt & 1);

    // C-init = rh + rw, masked to MNEG via policy bits (built while loads fly)
    unsigned int w = (unsigned int)mm0 & 0xFFFFu;
    mm0 = (mm0 >> 16) | (mm1 << 48);
    mm1 = (mm1 >> 16) | (mm2 << 48);
    mm2 = (mm2 >> 16) | (mm3 << 48);
    mm3 >>= 16;
    unsigned int rhp = RHb[qloc * 17 + kt];
    float rh0 = bfu2f(rhp & 0xffffu), rh1 = bfhi2f(rhp);
    floatx4 init[4];
#pragma unroll
    for (int t = 0; t < 4; ++t) {
      float rh = (t < 2) ? rh0 : rh1;
#pragma unroll
      for (int reg = 0; reg < 4; ++reg) {
        float base = rh + rwv[t & 1][reg];
        init[t][reg] = ((w >> ((t >> 1) * 8 + (t & 1) * 4 + reg)) & 1u) ? base : MNEG_;
      }
    }

    // S' = K.Q^T + init (rows = pi-permuted k tokens, cols = q)
    floatx4 s[4];
#pragma unroll
    for (int t = 0; t < 4; ++t) {
      int r = t * 16 + c16;
      bf16x8 ak0 = *(bf16x8*)&Ks[cur][r * 64 + (quad ^ sw) * 8];
      bf16x8 ak1 = *(bf16x8*)&Ks[cur][r * 64 + ((4 + quad) ^ sw) * 8];
      s[t] = MFMA16(ak1, qf1, MFMA16(ak0, qf0, init[t]));
    }

    // exp (raw v_exp_f32) -> +EPSN -> bf16 via COMPILER casts.
    // P' = e + EPS/N: numerator gets the reference's epsilon term for free
    // via the PV MFMA; masked entries become exactly EPSN (e==0 there).
    float ev[4][4];
#pragma unroll
    for (int t = 0; t < 4; ++t)
#pragma unroll
      for (int reg = 0; reg < 4; ++reg) ev[t][reg] = EXP2F(s[t][reg]) + EPSN_;

    // PV: O += P'.V, A-frag assembled in-register; l rides a ones-B MFMA
#pragma unroll
    for (int kw2 = 0; kw2 < 2; ++kw2) {
      bf16x8 apv;
#pragma unroll
      for (int j = 0; j < 8; ++j)
        apv[j] = (bf16)ev[2 * kw2 + (j >> 2)][j & 3];
      o_l = MFMA16(apv, vone, o_l);
#pragma unroll
      for (int dt = 0; dt < 4; ++dt) {
        int r = dt * 16 + c16;
        bf16x8 bv = *(bf16x8*)&Vt[cur][r * 64 + ((kw2 * 4 + quad) ^ sw) * 8];
        o_acc[dt] = MFMA16(apv, bv, o_acc[dt]);
      }
    }
  }

  // o_l[reg] = sum(P'+...) = sum(e) + 1024*EPSN = sum(e) + EPS — the exact
  // reference denominator for q = quad*4+reg. No +EPS, no shuffles.
  float inv[4];
#pragma unroll
  for (int reg = 0; reg < 4; ++reg) inv[reg] = 1.f / o_l[reg];

#pragma unroll
  for (int dt = 0; dt < 4; ++dt) {
    int d = dt * 16 + c16;
#pragma unroll
    for (int reg = 0; reg < 4; ++reg) {
      int nq = qt * 128 + wid * 16 + quad * 4 + reg;
      float o = o_acc[dt][reg] * inv[reg];
      AO[((size_t)b * N_ + nq) * C_ + head * HD_ + d] = (bf16)o;
    }
  }
}

// ---------------------------------------------------------------------------
// Proj GEMM, double-buffered LDS, flip orientation (float4 stores).
// ---------------------------------------------------------------------------
__global__ __launch_bounds__(256) void gemm_proj(
    const bf16* __restrict__ A, const bf16* __restrict__ W,
    const float* __restrict__ bias, float* __restrict__ Out) {
  __shared__ __align__(16) bf16 As[2][8192];
  __shared__ __align__(16) bf16 Bs[2][8192];
  const int tid = threadIdx.x;
  const int lane = tid & 63, quad = lane >> 4, c16 = lane & 15;
  const int wid = tid >> 6;
  const int wm = (wid >> 1) * 64, wn = (wid & 1) * 64;
  const int m0 = blockIdx.x * 128, n0 = blockIdx.y * 128;
  floatx4 acc[4][4];
#pragma unroll
  for (int i = 0; i < 4; ++i)
#pragma unroll
    for (int j = 0; j < 4; ++j) acc[i][j] = {0.f, 0.f, 0.f, 0.f};

  auto stage = [&](int k0, int buf) {
#pragma unroll
    for (int t = 0; t < 4; ++t) {
      int task = t * 256 + tid;
      int r = task >> 3, lg = (task & 7) ^ (r & 7);
      int wbase = (t * 256 + (tid & 192)) * 8;
      gld16(A + (size_t)(m0 + r) * 768 + k0 + lg * 8, &As[buf][wbase]);
      gld16(W + (size_t)(n0 + r) * 768 + k0 + lg * 8, &Bs[buf][wbase]);
    }
  };

  stage(0, 0);
  for (int it = 0; it < 12; ++it) {
    const int cur = it & 1;
    __syncthreads();
    if (it < 11) stage((it + 1) * 64, cur ^ 1);
#pragma unroll
    for (int kw = 0; kw < 2; ++kw) {
      bf16x8 af[4], bfr[4];
#pragma unroll
      for (int i = 0; i < 4; ++i) {
        int r = wm + i * 16 + c16, pg = (kw * 4 + quad) ^ (c16 & 7);
        af[i] = *(bf16x8*)&As[cur][r * 64 + pg * 8];
      }
#pragma unroll
      for (int j = 0; j < 4; ++j) {
        int r = wn + j * 16 + c16, pg = (kw * 4 + quad) ^ (c16 & 7);
        bfr[j] = *(bf16x8*)&Bs[cur][r * 64 + pg * 8];
      }
#pragma unroll
      for (int a = 0; a < 4; ++a)
#pragma unroll
        for (int b = 0; b < 4; ++b) acc[a][b] = MFMA16(bfr[a], af[b], acc[a][b]);
    }
  }
#pragma unroll
  for (int a = 0; a < 4; ++a) {
    int jb = n0 + wn + a * 16 + quad * 4;
    float4 b4 = *(const float4*)&bias[jb];
#pragma unroll
    for (int b = 0; b < 4; ++b) {
      int m = m0 + wm + b * 16 + c16;
      float4 o = make_float4(acc[a][b][0] + b4.x, acc[a][b][1] + b4.y,
                             acc[a][b][2] + b4.z, acc[a][b][3] + b4.w);
      *(float4*)&Out[(size_t)m * 768 + jb] = o;
    }
  }
}

extern "C" void kernel_launch(void* const* d_in, const int* in_sizes, int n_in,
                              void* d_out, int out_size, void* d_ws, size_t ws_size,
                              hipStream_t stream) {
  const float* x      = (const float*)d_in[0];
  const float* policy = (const float*)d_in[1];
  const float* qkv_w  = (const float*)d_in[2];
  const float* qkv_b  = (const float*)d_in[3];
  const float* proj_w = (const float*)d_in[4];
  const float* proj_b = (const float*)d_in[5];
  const float* relh   = (const float*)d_in[6];
  const float* relw   = (const float*)d_in[7];

  char* ws = (char*)d_ws;
  bf16* Xbf   = (bf16*)(ws);                    // 12,582,912 B
  bf16* Wqkv  = (bf16*)(ws + 12582912);         //  3,538,944 B
  bf16* Wproj = (bf16*)(ws + 16121856);         //  1,179,648 B
  bf16* Rhb   = (bf16*)(ws + 17301504);         //      8,192 B
  bf16* Rwb   = (bf16*)(ws + 17309696);         //      8,192 B
  bf16* Qb    = (bf16*)(ws + 17317888);         // 12,582,912 B
  bf16* Kb    = (bf16*)(ws + 29900800);
  bf16* Vb    = (bf16*)(ws + 42483712);         // [bh][d][n] layout
  bf16* AOb   = (bf16*)(ws + 55066624);

  prep_kernel<<<8480, 256, 0, stream>>>(x, qkv_w, proj_w, relh, relw,
                                        Xbf, Wqkv, Wproj, Rhb, Rwb);
  gemm_qkv<<<dim3(64, 18), 256, 0, stream>>>(Xbf, Wqkv, qkv_b, Qb, Kb, Vb);
  attn_mfma<<<dim3(BH_, 8), 512, 0, stream>>>(Qb, Kb, Vb, policy, Rhb, Rwb,
                                              AOb);
  gemm_proj<<<dim3(64, 6), 256, 0, stream>>>(AOb, Wproj, proj_b, (float*)d_out);
}

// Round 8
// 215.645 us; speedup vs baseline: 1.4255x; 1.0054x over previous
//
#include <hip/hip_runtime.h>
#include <hip/hip_bf16.h>

// Problem constants (reference: DIM=768, NUM_HEADS=12, HEAD_DIM=64, GRID=32, B=8)
#define B_   8
#define N_   1024
#define C_   768
#define NH_  12
#define HD_  64
#define BH_  96
#define EPS_ 1e-6f
#define EPSN_ (1e-6f / 1024.0f)
#define SQ_  0.1803368801111244f   // 0.125 * log2(e) — Q pre-scale
#define MASKV_ (-29.9315686f)      // log2(EPS/N): masked entries -> exp2 = EPSN

typedef __bf16 bf16;
typedef __attribute__((ext_vector_type(8))) __bf16  bf16x8;
typedef __attribute__((ext_vector_type(4))) __bf16  bf16x4;
typedef __attribute__((ext_vector_type(4))) float   floatx4;

#define MFMA16(a, b, c) __builtin_amdgcn_mfma_f32_16x16x32_bf16((a), (b), (c), 0, 0, 0)

// Fast exp2: raw v_exp_f32. Safe fallback is plain exp2f (known-good).
#if __has_builtin(__builtin_amdgcn_exp2f)
#define EXP2F(x) __builtin_amdgcn_exp2f(x)
#else
#define EXP2F(x) exp2f(x)
#endif

__device__ __forceinline__ void gld16(const void* g, void* l) {
  typedef unsigned int u32;
  __builtin_amdgcn_global_load_lds(
      (const __attribute__((address_space(1))) u32*)g,
      (__attribute__((address_space(3))) u32*)l, 16, 0, 0);
}
__device__ __forceinline__ float bfu2f(unsigned int u) {   // low 16 bits = bf16
  union { unsigned int i; float f; } v; v.i = u << 16; return v.f;
}
__device__ __forceinline__ float bfhi2f(unsigned int u) {  // high 16 bits = bf16
  union { unsigned int i; float f; } v; v.i = u & 0xffff0000u; return v.f;
}
__device__ __forceinline__ unsigned short f2bfu(float f) {
  union { float f; unsigned int i; } v; v.f = f;
  return (unsigned short)((v.i + 0x7FFFu + ((v.i >> 16) & 1u)) >> 16);
}

// ---------------------------------------------------------------------------
// Fused prep: x/qkv_w/proj_w fp32->bf16, rel tables fp32->bf16 scaled by 8.
// ---------------------------------------------------------------------------
__global__ __launch_bounds__(256) void prep_kernel(
    const float* __restrict__ x, const float* __restrict__ qkv_w,
    const float* __restrict__ proj_w, const float* __restrict__ relh,
    const float* __restrict__ relw,
    bf16* __restrict__ Xb, bf16* __restrict__ Wq, bf16* __restrict__ Wp,
    bf16* __restrict__ Rhb, bf16* __restrict__ Rwb) {
  int bid = blockIdx.x;
  if (bid < 8448) {                 // bulk converts
    const float* in; bf16* out; int i;
    if (bid < 6144)      { in = x;      out = Xb; i = bid * 256 + threadIdx.x; }
    else if (bid < 7872) { in = qkv_w;  out = Wq; i = (bid - 6144) * 256 + threadIdx.x; }
    else                 { in = proj_w; out = Wp; i = (bid - 7872) * 256 + threadIdx.x; }
    float4 v = ((const float4*)in)[i];
    bf16x4 o = {(bf16)v.x, (bf16)v.y, (bf16)v.z, (bf16)v.w};
    ((bf16x4*)out)[i] = o;
  } else {                          // rel tables: 63x64 -> 64x64, x8 scale
    const float* in = (bid < 8464) ? relh : relw;
    bf16* out = (bid < 8464) ? Rhb : Rwb;
    int i = ((bid < 8464) ? (bid - 8448) : (bid - 8464)) * 256 + threadIdx.x;
    int r = i >> 6;
    out[i] = (r < 63) ? (bf16)(in[i] * 8.0f) : (bf16)0.0f;
  }
}

// ---------------------------------------------------------------------------
// QKV GEMM, double-buffered LDS (unchanged).
// ---------------------------------------------------------------------------
__global__ __launch_bounds__(256) void gemm_qkv(
    const bf16* __restrict__ X, const bf16* __restrict__ W,
    const float* __restrict__ bias,
    bf16* __restrict__ Qb, bf16* __restrict__ Kb, bf16* __restrict__ Vb) {
  __shared__ __align__(16) bf16 As[2][8192];
  __shared__ __align__(16) bf16 Bs[2][8192];
  const int tid = threadIdx.x;
  const int lane = tid & 63, quad = lane >> 4, c16 = lane & 15;
  const int wid = tid >> 6;
  const int wm = (wid >> 1) * 64, wn = (wid & 1) * 64;
  const int m0 = blockIdx.x * 128, n0 = blockIdx.y * 128;
  const bool flip = (blockIdx.y < 12);    // Q and K column blocks
  floatx4 acc[4][4];
#pragma unroll
  for (int i = 0; i < 4; ++i)
#pragma unroll
    for (int j = 0; j < 4; ++j) acc[i][j] = {0.f, 0.f, 0.f, 0.f};

  auto stage = [&](int k0, int buf) {
#pragma unroll
    for (int t = 0; t < 4; ++t) {
      int task = t * 256 + tid;
      int r = task >> 3, lg = (task & 7) ^ (r & 7);
      int wbase = (t * 256 + (tid & 192)) * 8;
      gld16(X + (size_t)(m0 + r) * 768 + k0 + lg * 8, &As[buf][wbase]);
      gld16(W + (size_t)(n0 + r) * 768 + k0 + lg * 8, &Bs[buf][wbase]);
    }
  };

  stage(0, 0);
  for (int it = 0; it < 12; ++it) {
    const int cur = it & 1;
    __syncthreads();                       // drains stage(it); orders WAR for it+1
    if (it < 11) stage((it + 1) * 64, cur ^ 1);
#pragma unroll
    for (int kw = 0; kw < 2; ++kw) {
      bf16x8 af[4], bfr[4];
#pragma unroll
      for (int i = 0; i < 4; ++i) {
        int r = wm + i * 16 + c16, pg = (kw * 4 + quad) ^ (c16 & 7);
        af[i] = *(bf16x8*)&As[cur][r * 64 + pg * 8];
      }
#pragma unroll
      for (int j = 0; j < 4; ++j) {
        int r = wn + j * 16 + c16, pg = (kw * 4 + quad) ^ (c16 & 7);
        bfr[j] = *(bf16x8*)&Bs[cur][r * 64 + pg * 8];
      }
      if (flip) {
#pragma unroll
        for (int a = 0; a < 4; ++a)
#pragma unroll
          for (int b = 0; b < 4; ++b) acc[a][b] = MFMA16(bfr[a], af[b], acc[a][b]);
      } else {
#pragma unroll
        for (int i = 0; i < 4; ++i)
#pragma unroll
          for (int j = 0; j < 4; ++j) acc[i][j] = MFMA16(af[i], bfr[j], acc[i][j]);
      }
    }
  }
  if (flip) {
    const bool isQ = (blockIdx.y < 6);
    bf16* base = isQ ? Qb : Kb;
    const int off = isQ ? 0 : 768;
#pragma unroll
    for (int a = 0; a < 4; ++a) {
      int jb = n0 + wn + a * 16 + quad * 4;
      float4 b4 = *(const float4*)&bias[jb];
      int head = (jb - off) >> 6;
      int d = jb & 63;
#pragma unroll
      for (int b = 0; b < 4; ++b) {
        int tok = m0 + wm + b * 16 + c16;
        int bb = tok >> 10, n = tok & 1023;
        float v0 = acc[a][b][0] + b4.x, v1 = acc[a][b][1] + b4.y;
        float v2 = acc[a][b][2] + b4.z, v3 = acc[a][b][3] + b4.w;
        if (isQ) { v0 *= SQ_; v1 *= SQ_; v2 *= SQ_; v3 *= SQ_; }
        bf16x4 o = {(bf16)v0, (bf16)v1, (bf16)v2, (bf16)v3};
        *(bf16x4*)&base[(((size_t)bb * NH_ + head) * N_ + n) * HD_ + d] = o;
      }
    }
  } else {
#pragma unroll
    for (int jt = 0; jt < 4; ++jt) {
      int j = n0 + wn + jt * 16 + c16;
      float bj = bias[j];
      int rem = j - 1536, head = rem >> 6, d = rem & 63;
#pragma unroll
      for (int it = 0; it < 4; ++it) {
        int mbase = m0 + wm + it * 16 + quad * 4;
        int bb = mbase >> 10, n = mbase & 1023;
        bf16x4 o = {(bf16)(acc[it][jt][0] + bj), (bf16)(acc[it][jt][1] + bj),
                    (bf16)(acc[it][jt][2] + bj), (bf16)(acc[it][jt][3] + bj)};
        *(bf16x4*)&Vb[(((size_t)bb * NH_ + head) * HD_ + d) * N_ + n] = o;
      }
    }
  }
}

// ---------------------------------------------------------------------------
// Flash attention, R16: EPSN fold moved into the MASK CONSTANT. R7 post-
// mortem: the 16 `+EPSN` adds/kt (each a dependent hop on a TRANS-pipe
// v_exp_f32 result) cost 63.3->70.0us. Fix: masked C-init = log2(EPS/N)
// = -29.9316 instead of -3e38, so masked entries produce exp2(~-29.93)
// ~= EPSN directly; the PV MFMA and ones-MFMA then carry the reference's
// epsilon terms in numerator AND denominator with ZERO extra instructions.
// (Dropped unmasked-EPSN terms and the ~2^(+-2) perturbation on masked
// terms are ~1e-5 absolute — far under the 2.4e-3 threshold; the always-
// unmasked diagonal keeps every denominator >= O(e_diag).) Inner loop is
// byte-identical to R5's 63.3us stream; no vsum kernel, no Vsum read.
// ---------------------------------------------------------------------------
__global__ __launch_bounds__(512, 6) void attn_mfma(
    const bf16* __restrict__ Qb, const bf16* __restrict__ Kb,
    const bf16* __restrict__ Vb, const float* __restrict__ policy,
    const bf16* __restrict__ Rh, const bf16* __restrict__ Rw,
    bf16* __restrict__ AO) {
  const int bh = blockIdx.x, qt = blockIdx.y;      // qt: 128-row q tile index
  const int b = bh / NH_, head = bh % NH_;
  __shared__ __align__(16) bf16 Ks[2][4096];       // K tiles, pi-permuted rows
  __shared__ __align__(16) bf16 Vt[2][4096];       // V tiles [d][k]
  __shared__ unsigned int RHb[128 * 17];           // [q][kt] u32, stride-17 pad
  unsigned short* RWb = (unsigned short*)Ks;       // [q][kcol], prologue-only alias
  const int tid = threadIdx.x;
  const int wid = tid >> 6, lane = tid & 63, quad = lane >> 4, c16 = lane & 15;
  const int sw = c16 & 7;
  const int qloc = wid * 16 + c16;                 // this lane's q row [0,128)
  const floatx4 zero4 = {0.f, 0.f, 0.f, 0.f};

  const bf16* Qg = Qb + ((size_t)bh * N_ + qt * 128) * HD_;
  const bf16* Kg = Kb + (size_t)bh * (N_ * HD_);
  const bf16* Vg = Vb + (size_t)bh * (N_ * HD_);

  // Staging: tid-only address parts hoisted once; per-kt only the tile
  // offset varies. K rows pi-permuted + column-XOR via the global SOURCE
  // address (LDS dest stays linear, wave-uniform base + lane*16).
  const int sp = tid >> 3, sg = tid & 7;
  const int Tk = 32 * (sp >> 5) + 4 * ((sp >> 4) & 1) + 8 * ((sp >> 2) & 3) + (sp & 3);
  const int koff = (sg ^ (sp & 7)) * 8;
  const bf16* kbase = Kg + (size_t)Tk * 64 + koff;
  const bf16* vbase = Vg + (size_t)sp * N_ + koff;
  const int wbase = (tid & 448) * 8;               // wave-uniform LDS base
  auto stageKV = [&](int kt2, int buf) {
    gld16(kbase + (size_t)kt2 * 4096, &Ks[buf][wbase]);
    gld16(vbase + kt2 * 64, &Vt[buf][wbase]);
  };

  // K/V tile 0 -> buffer 1; latency hides under the whole prologue
  stageKV(0, 1);

  // policy -> per-thread packed mask bits (16 bits per kt). Diagonal k tile
  // is per-thread: dkt = 2*qt + (qloc>>6); k-in-tile kd = qloc&63.
  unsigned long long p64[4] = {0ull, 0ull, 0ull, 0ull};
  {
    const float* Pg = policy + (size_t)b * N_;
    const int kd = qloc & 63;
    const int dkt = 2 * qt + (qloc >> 6);
#pragma unroll
    for (int kt = 0; kt < 16; ++kt) {
      unsigned long long bal = __ballot(Pg[kt * 64 + lane] != 0.0f);
      unsigned int w16 = (((unsigned int)bal >> (8 * quad)) & 0xFFu)
                       | ((((unsigned int)(bal >> 32) >> (8 * quad)) & 0xFFu) << 8);
      if (kt == dkt && quad == ((kd >> 3) & 3))
        w16 |= 1u << (((kd >> 5) << 3) | (kd & 7));   // diagonal unmasked
      p64[kt >> 2] |= (unsigned long long)w16 << (16 * (kt & 3));
    }
  }

  // Q fragments straight from global (A- and B-role layouts are identical)
  bf16x8 qf0 = *(const bf16x8*)(Qg + qloc * 64 + quad * 8);
  bf16x8 qf1 = *(const bf16x8*)(Qg + qloc * 64 + 32 + quad * 8);

  // QRh -> RHb[q][kgr] (bf16 bits; rows wave-private). Rh B-frags from global.
  {
    floatx4 racc[4];
#pragma unroll
    for (int nt = 0; nt < 4; ++nt) {
      int r = nt * 16 + c16;
      bf16x8 b0 = *(const bf16x8*)(Rh + r * 64 + quad * 8);
      bf16x8 b1 = *(const bf16x8*)(Rh + r * 64 + 32 + quad * 8);
      racc[nt] = MFMA16(qf1, b1, MFMA16(qf0, b0, zero4));
    }
#pragma unroll
    for (int nt = 0; nt < 4; ++nt)
#pragma unroll
      for (int reg = 0; reg < 4; ++reg) {
        int rloc = wid * 16 + quad * 4 + reg;
        int hh = 4 * qt + (rloc >> 5);             // global h of q row rloc
        int krow = hh + 31 - (nt * 16 + c16);
        if ((unsigned)krow < 32u)
          ((unsigned short*)RHb)[rloc * 34 + krow] = f2bfu(racc[nt][reg]);
      }
  }
  // QRw -> RWb[q][kcol]
  {
    floatx4 racc[4];
#pragma unroll
    for (int nt = 0; nt < 4; ++nt) {
      int r = nt * 16 + c16;
      bf16x8 b0 = *(const bf16x8*)(Rw + r * 64 + quad * 8);
      bf16x8 b1 = *(const bf16x8*)(Rw + r * 64 + 32 + quad * 8);
      racc[nt] = MFMA16(qf1, b1, MFMA16(qf0, b0, zero4));
    }
#pragma unroll
    for (int nt = 0; nt < 4; ++nt)
#pragma unroll
      for (int reg = 0; reg < 4; ++reg) {
        int rloc = wid * 16 + quad * 4 + reg;
        int kcol = (rloc & 31) + 31 - (nt * 16 + c16);   // qg&31 == rloc&31
        if ((unsigned)kcol < 32u) RWb[rloc * 32 + kcol] = f2bfu(racc[nt][reg]);
      }
  }

  // hoist rw: lane's slot (t,reg) has kcol = 8*quad+4*(t&1)+reg (kt-invariant)
  float rwv[2][4];
#pragma unroll
  for (int p = 0; p < 2; ++p)
#pragma unroll
    for (int reg = 0; reg < 4; ++reg)
      rwv[p][reg] = bfu2f(RWb[qloc * 32 + 8 * quad + 4 * p + reg]);

  floatx4 o_acc[4];
#pragma unroll
  for (int i = 0; i < 4; ++i) o_acc[i] = zero4;
  floatx4 o_l = zero4;                             // l via MFMA(P', ones)
  bf16x8 vone;
#pragma unroll
  for (int e = 0; e < 8; ++e) vone[e] = (bf16)1.0f;

  // 256-bit mask shift chain (no runtime-indexed register arrays)
  unsigned long long mm0 = p64[0], mm1 = p64[1], mm2 = p64[2], mm3 = p64[3];

  // tile kt lives in buffer (kt+1)&1 (tile 0 went to buf 1)
  for (int kt = 0; kt < 16; ++kt) {
    const int cur = (kt + 1) & 1;
    __syncthreads();                 // drains stage(kt); orders WAR for stage(kt+1)
    if (kt < 15) stageKV(kt + 1, kt & 1);

    // C-init = rh + rw, masked to MASKV_ (-> exp2 = EPSN) via policy bits
    unsigned int w = (unsigned int)mm0 & 0xFFFFu;
    mm0 = (mm0 >> 16) | (mm1 << 48);
    mm1 = (mm1 >> 16) | (mm2 << 48);
    mm2 = (mm2 >> 16) | (mm3 << 48);
    mm3 >>= 16;
    unsigned int rhp = RHb[qloc * 17 + kt];
    float rh0 = bfu2f(rhp & 0xffffu), rh1 = bfhi2f(rhp);
    floatx4 init[4];
#pragma unroll
    for (int t = 0; t < 4; ++t) {
      float rh = (t < 2) ? rh0 : rh1;
#pragma unroll
      for (int reg = 0; reg < 4; ++reg) {
        float base = rh + rwv[t & 1][reg];
        init[t][reg] = ((w >> ((t >> 1) * 8 + (t & 1) * 4 + reg)) & 1u) ? base : MASKV_;
      }
    }

    // S' = K.Q^T + init (rows = pi-permuted k tokens, cols = q)
    floatx4 s[4];
#pragma unroll
    for (int t = 0; t < 4; ++t) {
      int r = t * 16 + c16;
      bf16x8 ak0 = *(bf16x8*)&Ks[cur][r * 64 + (quad ^ sw) * 8];
      bf16x8 ak1 = *(bf16x8*)&Ks[cur][r * 64 + ((4 + quad) ^ sw) * 8];
      s[t] = MFMA16(ak1, qf1, MFMA16(ak0, qf0, init[t]));
    }

    // exp (raw v_exp_f32) -> bf16 via COMPILER casts (hazard-scheduled).
    // Masked entries come out as ~EPSN; no per-element epsilon adds.
    float ev[4][4];
#pragma unroll
    for (int t = 0; t < 4; ++t)
#pragma unroll
      for (int reg = 0; reg < 4; ++reg) ev[t][reg] = EXP2F(s[t][reg]);

    // PV: O += P'.V, A-frag assembled in-register; l rides a ones-B MFMA
#pragma unroll
    for (int kw2 = 0; kw2 < 2; ++kw2) {
      bf16x8 apv;
#pragma unroll
      for (int j = 0; j < 8; ++j)
        apv[j] = (bf16)ev[2 * kw2 + (j >> 2)][j & 3];
      o_l = MFMA16(apv, vone, o_l);
#pragma unroll
      for (int dt = 0; dt < 4; ++dt) {
        int r = dt * 16 + c16;
        bf16x8 bv = *(bf16x8*)&Vt[cur][r * 64 + ((kw2 * 4 + quad) ^ sw) * 8];
        o_acc[dt] = MFMA16(apv, bv, o_acc[dt]);
      }
    }
  }

  // o_l[reg] = sum(P') ~= sum(e) + (masked count)*EPSN — the reference
  // denominator within ~1e-6 relative. q = quad*4+reg; no shuffles.
  float inv[4];
#pragma unroll
  for (int reg = 0; reg < 4; ++reg) inv[reg] = 1.f / o_l[reg];

#pragma unroll
  for (int dt = 0; dt < 4; ++dt) {
    int d = dt * 16 + c16;
#pragma unroll
    for (int reg = 0; reg < 4; ++reg) {
      int nq = qt * 128 + wid * 16 + quad * 4 + reg;
      float o = o_acc[dt][reg] * inv[reg];
      AO[((size_t)b * N_ + nq) * C_ + head * HD_ + d] = (bf16)o;
    }
  }
}

// ---------------------------------------------------------------------------
// Proj GEMM, double-buffered LDS, flip orientation (float4 stores).
// ---------------------------------------------------------------------------
__global__ __launch_bounds__(256) void gemm_proj(
    const bf16* __restrict__ A, const bf16* __restrict__ W,
    const float* __restrict__ bias, float* __restrict__ Out) {
  __shared__ __align__(16) bf16 As[2][8192];
  __shared__ __align__(16) bf16 Bs[2][8192];
  const int tid = threadIdx.x;
  const int lane = tid & 63, quad = lane >> 4, c16 = lane & 15;
  const int wid = tid >> 6;
  const int wm = (wid >> 1) * 64, wn = (wid & 1) * 64;
  const int m0 = blockIdx.x * 128, n0 = blockIdx.y * 128;
  floatx4 acc[4][4];
#pragma unroll
  for (int i = 0; i < 4; ++i)
#pragma unroll
    for (int j = 0; j < 4; ++j) acc[i][j] = {0.f, 0.f, 0.f, 0.f};

  auto stage = [&](int k0, int buf) {
#pragma unroll
    for (int t = 0; t < 4; ++t) {
      int task = t * 256 + tid;
      int r = task >> 3, lg = (task & 7) ^ (r & 7);
      int wbase = (t * 256 + (tid & 192)) * 8;
      gld16(A + (size_t)(m0 + r) * 768 + k0 + lg * 8, &As[buf][wbase]);
      gld16(W + (size_t)(n0 + r) * 768 + k0 + lg * 8, &Bs[buf][wbase]);
    }
  };

  stage(0, 0);
  for (int it = 0; it < 12; ++it) {
    const int cur = it & 1;
    __syncthreads();
    if (it < 11) stage((it + 1) * 64, cur ^ 1);
#pragma unroll
    for (int kw = 0; kw < 2; ++kw) {
      bf16x8 af[4], bfr[4];
#pragma unroll
      for (int i = 0; i < 4; ++i) {
        int r = wm + i * 16 + c16, pg = (kw * 4 + quad) ^ (c16 & 7);
        af[i] = *(bf16x8*)&As[cur][r * 64 + pg * 8];
      }
#pragma unroll
      for (int j = 0; j < 4; ++j) {
        int r = wn + j * 16 + c16, pg = (kw * 4 + quad) ^ (c16 & 7);
        bfr[j] = *(bf16x8*)&Bs[cur][r * 64 + pg * 8];
      }
#pragma unroll
      for (int a = 0; a < 4; ++a)
#pragma unroll
        for (int b = 0; b < 4; ++b) acc[a][b] = MFMA16(bfr[a], af[b], acc[a][b]);
    }
  }
#pragma unroll
  for (int a = 0; a < 4; ++a) {
    int jb = n0 + wn + a * 16 + quad * 4;
    float4 b4 = *(const float4*)&bias[jb];
#pragma unroll
    for (int b = 0; b < 4; ++b) {
      int m = m0 + wm + b * 16 + c16;
      float4 o = make_float4(acc[a][b][0] + b4.x, acc[a][b][1] + b4.y,
                             acc[a][b][2] + b4.z, acc[a][b][3] + b4.w);
      *(float4*)&Out[(size_t)m * 768 + jb] = o;
    }
  }
}

extern "C" void kernel_launch(void* const* d_in, const int* in_sizes, int n_in,
                              void* d_out, int out_size, void* d_ws, size_t ws_size,
                              hipStream_t stream) {
  const float* x      = (const float*)d_in[0];
  const float* policy = (const float*)d_in[1];
  const float* qkv_w  = (const float*)d_in[2];
  const float* qkv_b  = (const float*)d_in[3];
  const float* proj_w = (const float*)d_in[4];
  const float* proj_b = (const float*)d_in[5];
  const float* relh   = (const float*)d_in[6];
  const float* relw   = (const float*)d_in[7];

  char* ws = (char*)d_ws;
  bf16* Xbf   = (bf16*)(ws);                    // 12,582,912 B
  bf16* Wqkv  = (bf16*)(ws + 12582912);         //  3,538,944 B
  bf16* Wproj = (bf16*)(ws + 16121856);         //  1,179,648 B
  bf16* Rhb   = (bf16*)(ws + 17301504);         //      8,192 B
  bf16* Rwb   = (bf16*)(ws + 17309696);         //      8,192 B
  bf16* Qb    = (bf16*)(ws + 17317888);         // 12,582,912 B
  bf16* Kb    = (bf16*)(ws + 29900800);
  bf16* Vb    = (bf16*)(ws + 42483712);         // [bh][d][n] layout
  bf16* AOb   = (bf16*)(ws + 55066624);

  prep_kernel<<<8480, 256, 0, stream>>>(x, qkv_w, proj_w, relh, relw,
                                        Xbf, Wqkv, Wproj, Rhb, Rwb);
  gemm_qkv<<<dim3(64, 18), 256, 0, stream>>>(Xbf, Wqkv, qkv_b, Qb, Kb, Vb);
  attn_mfma<<<dim3(BH_, 8), 512, 0, stream>>>(Qb, Kb, Vb, policy, Rhb, Rwb,
                                              AOb);
  gemm_proj<<<dim3(64, 6), 256, 0, stream>>>(AOb, Wproj, proj_b, (float*)d_out);
}